// Round 1
// baseline (192.703 us; speedup 1.0000x reference)
//
#include <hip/hip_runtime.h>
#include <math.h>

#define MAXF 512
#define BZ   32
#define DD   1024
#define HH   16
#define OO   4
#define SS   64
#define FCH  4096
#define KPARTS 8

typedef __attribute__((ext_vector_type(8))) short short8;   // 8 x bf16 (4 VGPR)
typedef __attribute__((ext_vector_type(4))) float f32x4;

// round-to-nearest-even f32 -> bf16 bit pattern
__device__ inline short f2bf(float f) {
    unsigned u = __float_as_uint(f);
    u += 0x7FFFu + ((u >> 16) & 1u);
    return (short)(u >> 16);
}

// ---- 4-wide helpers (all static-indexed; rule #20 safe) ----------------------
#define MUL4(A,S)  do{ (A).x*=(S); (A).y*=(S); (A).z*=(S); (A).w*=(S); }while(0)
#define FMA4(A,P,V) do{ (A).x += (P)*(V).x; (A).y += (P)*(V).y; \
                        (A).z += (P)*(V).z; (A).w += (P)*(V).w; }while(0)
// butterfly over the frame bits (lane bits 2..5); sg (bits 0,1) untouched
#define RSUMF(F) do{ F += __shfl_xor(F,4,64); F += __shfl_xor(F,8,64); \
                     F += __shfl_xor(F,16,64); F += __shfl_xor(F,32,64); }while(0)
#define RMAXF(F) do{ F = fmaxf(F,__shfl_xor(F,4,64)); F = fmaxf(F,__shfl_xor(F,8,64)); \
                     F = fmaxf(F,__shfl_xor(F,16,64)); F = fmaxf(F,__shfl_xor(F,32,64)); }while(0)
#define BFLY4(A) do{ RSUMF((A).x); RSUMF((A).y); RSUMF((A).z); RSUMF((A).w); }while(0)
// compile-time component select (J is a constant in unrolled loops -> folds)
#define CCOMP(V,C) ((C)==0?(V).x:(C)==1?(V).y:(C)==2?(V).z:(V).w)
#define GETJ(V0,V1,V2,V3,J) ((J)<4?CCOMP(V0,(J)&3):(J)<8?CCOMP(V1,(J)&3): \
                             (J)<12?CCOMP(V2,(J)&3):CCOMP(V3,(J)&3))
// dot over this thread's 16 s-values (xa0..xa3 in scope)
#define DOT16(R,QA,QB,QC,QD) \
    R = xa0.x*(QA).x + xa0.y*(QA).y + xa0.z*(QA).z + xa0.w*(QA).w \
      + xa1.x*(QB).x + xa1.y*(QB).y + xa1.z*(QB).z + xa1.w*(QB).w \
      + xa2.x*(QC).x + xa2.y*(QC).y + xa2.z*(QC).z + xa2.w*(QC).w \
      + xa3.x*(QD).x + xa3.y*(QD).y + xa3.z*(QD).z + xa3.w*(QD).w
#define SCALE_ACC() do{ \
    MUL4(a00,sc0);MUL4(a01,sc0);MUL4(a02,sc0);MUL4(a03,sc0); \
    MUL4(a10,sc1);MUL4(a11,sc1);MUL4(a12,sc1);MUL4(a13,sc1); \
    MUL4(a20,sc2);MUL4(a21,sc2);MUL4(a22,sc2);MUL4(a23,sc2); \
    MUL4(a30,sc3);MUL4(a31,sc3);MUL4(a32,sc3);MUL4(a33,sc3); }while(0)

// ---------------------------------------------------------------------------
// KA: fused attention. One block per (b,h); 256 threads = (fch = tid>>2) x
// (sg = tid&3). Thread owns s-values {4*sg + 16*i + c : i,c in 0..3} of its
// frame, keeping x in registers (no LDS tile, no bank conflicts, no atomics).
// Each wave runs an ONLINE softmax over its private 16-frames-per-chunk slice
// (no per-chunk barriers); waves merge once at the end through 4 KB of LDS.
// Writes: raw logits (-50 masked), final (m, 1/s) per (bh,o), hcat (direct).
// ---------------------------------------------------------------------------
__global__ __launch_bounds__(256) void attn_fused_kernel(
    const float* __restrict__ x, const int* __restrict__ num_frames,
    const float* __restrict__ query, float* __restrict__ logits,
    float2* __restrict__ fstats, float* __restrict__ hcat)
{
    __shared__ __align__(16) float sq[OO][SS];          // 1 KB
    __shared__ float wmS[4][OO], wsS[4][OO];            // per-wave stats
    __shared__ __align__(16) float accsh[4][4][16][OO]; // [w][sg][j][o] 4 KB

    const int tid  = threadIdx.x;
    const int bh   = blockIdx.x;
    const int b    = bh >> 4, h = bh & 15;
    const int nf   = num_frames[b];
    const int w    = tid >> 6;
    const int lane = tid & 63;
    const int sg   = tid & 3;
    const int fch  = tid >> 2;        // chunk-local frame 0..63

    sq[w][lane] = query[(size_t)(w * HH + h) * SS + lane];
    __syncthreads();

    // query fragments in registers: q[o][i] = query[o][h][4*sg + 16*i .. +3]
    float4 q00,q01,q02,q03,q10,q11,q12,q13,q20,q21,q22,q23,q30,q31,q32,q33;
    {
        const float4* q0 = (const float4*)&sq[0][0];
        q00=q0[sg]; q01=q0[sg+4]; q02=q0[sg+8]; q03=q0[sg+12];
        const float4* q1 = (const float4*)&sq[1][0];
        q10=q1[sg]; q11=q1[sg+4]; q12=q1[sg+8]; q13=q1[sg+12];
        const float4* q2 = (const float4*)&sq[2][0];
        q20=q2[sg]; q21=q2[sg+4]; q22=q2[sg+8]; q23=q2[sg+12];
        const float4* q3 = (const float4*)&sq[3][0];
        q30=q3[sg]; q31=q3[sg+4]; q32=q3[sg+8]; q33=q3[sg+12];
    }

    const float* xbase = x + (size_t)b * DD + (size_t)h * SS;

    float m0=-1e30f,m1=-1e30f,m2=-1e30f,m3=-1e30f;   // per-wave running max
    float s0=0.f,s1=0.f,s2=0.f,s3=0.f;               // per-wave running sum
    float4 a00={0,0,0,0},a01={0,0,0,0},a02={0,0,0,0},a03={0,0,0,0};
    float4 a10={0,0,0,0},a11={0,0,0,0},a12={0,0,0,0},a13={0,0,0,0};
    float4 a20={0,0,0,0},a21={0,0,0,0},a22={0,0,0,0},a23={0,0,0,0};
    float4 a30={0,0,0,0},a31={0,0,0,0},a32={0,0,0,0},a33={0,0,0,0};

    float4 xa0,xa1,xa2,xa3;
    {   // chunk 0 is always active (nf >= 1)
        const float4* p = (const float4*)(xbase + (size_t)fch * (BZ*DD));
        xa0=p[sg]; xa1=p[sg+4]; xa2=p[sg+8]; xa3=p[sg+12];
    }

    #pragma unroll
    for (int fc = 0; fc < 8; ++fc) {
        const int fbase = fc * 64;
        const bool act  = (fbase < nf);               // block-uniform
        float4 xb0={0,0,0,0},xb1={0,0,0,0},xb2={0,0,0,0},xb3={0,0,0,0};
        const bool actn = (fc < 7) && (fbase + 64 < nf);
        if (actn) {   // prefetch next chunk; no barrier anywhere in this loop
            const float4* p = (const float4*)(xbase + (size_t)(fbase + 64 + fch) * (BZ*DD));
            xb0=p[sg]; xb1=p[sg+4]; xb2=p[sg+8]; xb3=p[sg+12];
        }
        if (act) {
            float d0,d1,d2,d3;
            DOT16(d0,q00,q01,q02,q03);
            DOT16(d1,q10,q11,q12,q13);
            DOT16(d2,q20,q21,q22,q23);
            DOT16(d3,q30,q31,q32,q33);
            // complete dot across the sg-quad (lane bits 0,1)
            d0 += __shfl_xor(d0,1,64); d0 += __shfl_xor(d0,2,64);
            d1 += __shfl_xor(d1,1,64); d1 += __shfl_xor(d1,2,64);
            d2 += __shfl_xor(d2,1,64); d2 += __shfl_xor(d2,2,64);
            d3 += __shfl_xor(d3,1,64); d3 += __shfl_xor(d3,2,64);
            const bool valid = (fbase + fch) < nf;
            float lg0 = valid ? d0 * 0.125f : -50.f;
            float lg1 = valid ? d1 * 0.125f : -50.f;
            float lg2 = valid ? d2 * 0.125f : -50.f;
            float lg3 = valid ? d3 * 0.125f : -50.f;
            // wave-local chunk max over its 16 frames
            float c0=lg0,c1=lg1,c2=lg2,c3=lg3;
            RMAXF(c0); RMAXF(c1); RMAXF(c2); RMAXF(c3);
            float n0=fmaxf(m0,c0), n1=fmaxf(m1,c1), n2=fmaxf(m2,c2), n3=fmaxf(m3,c3);
            float e0=__expf(lg0-n0), e1=__expf(lg1-n1), e2=__expf(lg2-n2), e3=__expf(lg3-n3);
            float t0=e0,t1=e1,t2=e2,t3=e3;     // denominator includes -50 terms
            RSUMF(t0); RSUMF(t1); RSUMF(t2); RSUMF(t3);
            float sc0=__expf(m0-n0), sc1=__expf(m1-n1), sc2=__expf(m2-n2), sc3=__expf(m3-n3);
            s0 = s0*sc0 + t0; s1 = s1*sc1 + t1; s2 = s2*sc2 + t2; s3 = s3*sc3 + t3;
            m0=n0; m1=n1; m2=n2; m3=n3;
            if (sc0<1.f || sc1<1.f || sc2<1.f || sc3<1.f) SCALE_ACC();  // wave-uniform
            float p0 = valid ? e0 : 0.f;       // padded frames excluded from numerator
            float p1 = valid ? e1 : 0.f;
            float p2 = valid ? e2 : 0.f;
            float p3 = valid ? e3 : 0.f;
            FMA4(a00,p0,xa0); FMA4(a01,p0,xa1); FMA4(a02,p0,xa2); FMA4(a03,p0,xa3);
            FMA4(a10,p1,xa0); FMA4(a11,p1,xa1); FMA4(a12,p1,xa2); FMA4(a13,p1,xa3);
            FMA4(a20,p2,xa0); FMA4(a21,p2,xa1); FMA4(a22,p2,xa2); FMA4(a23,p2,xa3);
            FMA4(a30,p3,xa0); FMA4(a31,p3,xa1); FMA4(a32,p3,xa2); FMA4(a33,p3,xa3);
            float lgw = sg==0?lg0 : sg==1?lg1 : sg==2?lg2 : lg3;
            logits[((size_t)bh*OO + sg)*MAXF + fbase + fch] = lgw;
        } else {
            // fully padded chunk: 16 frames at -50 per wave (exact semantics)
            float n0=fmaxf(m0,-50.f), n1=fmaxf(m1,-50.f), n2=fmaxf(m2,-50.f), n3=fmaxf(m3,-50.f);
            float sc0=__expf(m0-n0), sc1=__expf(m1-n1), sc2=__expf(m2-n2), sc3=__expf(m3-n3);
            s0 = s0*sc0 + 16.f*__expf(-50.f-n0);
            s1 = s1*sc1 + 16.f*__expf(-50.f-n1);
            s2 = s2*sc2 + 16.f*__expf(-50.f-n2);
            s3 = s3*sc3 + 16.f*__expf(-50.f-n3);
            if (sc0<1.f || sc1<1.f || sc2<1.f || sc3<1.f) SCALE_ACC();
            m0=n0; m1=n1; m2=n2; m3=n3;
            logits[((size_t)bh*OO + sg)*MAXF + fbase + fch] = -50.f;
        }
        xa0=xb0; xa1=xb1; xa2=xb2; xa3=xb3;
    }

    // ---- cross-wave merge (once) ----
    if (lane == 0) {
        wmS[w][0]=m0; wmS[w][1]=m1; wmS[w][2]=m2; wmS[w][3]=m3;
        wsS[w][0]=s0; wsS[w][1]=s1; wsS[w][2]=s2; wsS[w][3]=s3;
    }
    __syncthreads();
    float gm0 = fmaxf(fmaxf(wmS[0][0],wmS[1][0]), fmaxf(wmS[2][0],wmS[3][0]));
    float gm1 = fmaxf(fmaxf(wmS[0][1],wmS[1][1]), fmaxf(wmS[2][1],wmS[3][1]));
    float gm2 = fmaxf(fmaxf(wmS[0][2],wmS[1][2]), fmaxf(wmS[2][2],wmS[3][2]));
    float gm3 = fmaxf(fmaxf(wmS[0][3],wmS[1][3]), fmaxf(wmS[2][3],wmS[3][3]));
    float gs0 = wsS[0][0]*__expf(wmS[0][0]-gm0) + wsS[1][0]*__expf(wmS[1][0]-gm0)
              + wsS[2][0]*__expf(wmS[2][0]-gm0) + wsS[3][0]*__expf(wmS[3][0]-gm0);
    float gs1 = wsS[0][1]*__expf(wmS[0][1]-gm1) + wsS[1][1]*__expf(wmS[1][1]-gm1)
              + wsS[2][1]*__expf(wmS[2][1]-gm1) + wsS[3][1]*__expf(wmS[3][1]-gm1);
    float gs2 = wsS[0][2]*__expf(wmS[0][2]-gm2) + wsS[1][2]*__expf(wmS[1][2]-gm2)
              + wsS[2][2]*__expf(wmS[2][2]-gm2) + wsS[3][2]*__expf(wmS[3][2]-gm2);
    float gs3 = wsS[0][3]*__expf(wmS[0][3]-gm3) + wsS[1][3]*__expf(wmS[1][3]-gm3)
              + wsS[2][3]*__expf(wmS[2][3]-gm3) + wsS[3][3]*__expf(wmS[3][3]-gm3);
    float scl0=__expf(m0-gm0), scl1=__expf(m1-gm1), scl2=__expf(m2-gm2), scl3=__expf(m3-gm3);

    // reduce acc over the wave's 16 frame-lanes (sg preserved)
    BFLY4(a00); BFLY4(a01); BFLY4(a02); BFLY4(a03);
    BFLY4(a10); BFLY4(a11); BFLY4(a12); BFLY4(a13);
    BFLY4(a20); BFLY4(a21); BFLY4(a22); BFLY4(a23);
    BFLY4(a30); BFLY4(a31); BFLY4(a32); BFLY4(a33);

    if ((lane >> 2) == 0) {   // 4 writer lanes per wave (sg = lane), static j
        #pragma unroll
        for (int j = 0; j < 16; ++j) {
            float v0 = GETJ(a00,a01,a02,a03,j) * scl0;
            float v1 = GETJ(a10,a11,a12,a13,j) * scl1;
            float v2 = GETJ(a20,a21,a22,a23,j) * scl2;
            float v3 = GETJ(a30,a31,a32,a33,j) * scl3;
            *(float4*)&accsh[w][sg][j][0] = make_float4(v0,v1,v2,v3);
        }
    }
    __syncthreads();
    {
        const int oo = tid >> 6, s = tid & 63;
        const int ssg = (s >> 2) & 3, sj = ((s >> 4) << 2) | (s & 3);
        float v = accsh[0][ssg][sj][oo] + accsh[1][ssg][sj][oo]
                + accsh[2][ssg][sj][oo] + accsh[3][ssg][sj][oo];
        float gso = oo==0?gs0 : oo==1?gs1 : oo==2?gs2 : gs3;
        hcat[(size_t)b*FCH + (size_t)oo*(HH*SS) + h*SS + s] = v * (1.0f/gso);
    }
    if (tid == 0) {
        fstats[bh*OO+0] = make_float2(gm0, 1.0f/gs0);
        fstats[bh*OO+1] = make_float2(gm1, 1.0f/gs1);
        fstats[bh*OO+2] = make_float2(gm2, 1.0f/gs2);
        fstats[bh*OO+3] = make_float2(gm3, 1.0f/gs3);
    }
}

// ---------------------------------------------------------------------------
// K3: attn output = transpose + normalize from raw logits + final stats.
// ---------------------------------------------------------------------------
__global__ __launch_bounds__(256) void attn_out_kernel(
    const float* __restrict__ logits, const float2* __restrict__ fstats,
    float* __restrict__ attn_out)
{
    __shared__ float tile[64][65];
    __shared__ float sm[64], sv[64];
    const int o     = blockIdx.z;
    const int fbase = blockIdx.x * 64;
    const int gbase = blockIdx.y * 64;   // bh tile base
    const int c  = threadIdx.x & 63;
    const int r4 = threadIdx.x >> 6;

    if (threadIdx.x < 64) {
        float2 st = fstats[(gbase + threadIdx.x) * OO + o];
        sm[threadIdx.x] = st.x;
        sv[threadIdx.x] = st.y;
    }
    for (int r = r4; r < 64; r += 4)
        tile[r][c] = logits[((size_t)(gbase + r) * OO + o) * MAXF + fbase + c];
    __syncthreads();
    for (int r = r4; r < 64; r += 4)
        attn_out[((size_t)o * MAXF + fbase + r) * (BZ * HH) + gbase + c] =
            __expf(tile[c][r] - sm[c]) * sv[c];
}

// ---------------------------------------------------------------------------
// K4: fc1 via bf16 MFMA (fp32 accumulate). part[kp][b][j] = partial GEMM over
// k in [kp*512, kp*512+512). grid (64 n-groups x 8 kp) = 512 blocks, no LDS,
// no atomics: every (kp,b,j) has a unique owner.
// ---------------------------------------------------------------------------
__global__ __launch_bounds__(256) void fc1_mfma_kernel(
    const float* __restrict__ hcat, const float* __restrict__ W1,
    float* __restrict__ part)
{
    const int tid  = threadIdx.x;
    const int w    = tid >> 6;
    const int lane = tid & 63;
    const int L15  = lane & 15, q = lane >> 4;
    const int j0   = blockIdx.x * 64 + w * 16;   // n-tile base (this wave)
    const int kp   = blockIdx.y;                 // 0..7
    const int k0   = kp * 512;

    f32x4 acc0 = {0.f, 0.f, 0.f, 0.f};          // m-rows 0..15  (b 0..15)
    f32x4 acc1 = {0.f, 0.f, 0.f, 0.f};          // m-rows 16..31 (b 16..31)

    #pragma unroll 2
    for (int s = 0; s < 16; ++s) {
        const int kk = k0 + s * 32 + q * 8;     // this lane's k-octet base

        const float4* a0p = (const float4*)(hcat + (size_t)L15 * FCH + kk);
        const float4* a1p = (const float4*)(hcat + (size_t)(L15 + 16) * FCH + kk);
        float4 a0l = a0p[0], a0h = a0p[1];
        float4 a1l = a1p[0], a1h = a1p[1];
        short8 af0, af1;
        af0[0]=f2bf(a0l.x); af0[1]=f2bf(a0l.y); af0[2]=f2bf(a0l.z); af0[3]=f2bf(a0l.w);
        af0[4]=f2bf(a0h.x); af0[5]=f2bf(a0h.y); af0[6]=f2bf(a0h.z); af0[7]=f2bf(a0h.w);
        af1[0]=f2bf(a1l.x); af1[1]=f2bf(a1l.y); af1[2]=f2bf(a1l.z); af1[3]=f2bf(a1l.w);
        af1[4]=f2bf(a1h.x); af1[5]=f2bf(a1h.y); af1[6]=f2bf(a1h.z); af1[7]=f2bf(a1h.w);

        const float* bp = W1 + (size_t)kk * FCH + j0 + L15;
        short8 bf;
        bf[0] = f2bf(bp[0 * (size_t)FCH]);
        bf[1] = f2bf(bp[1 * (size_t)FCH]);
        bf[2] = f2bf(bp[2 * (size_t)FCH]);
        bf[3] = f2bf(bp[3 * (size_t)FCH]);
        bf[4] = f2bf(bp[4 * (size_t)FCH]);
        bf[5] = f2bf(bp[5 * (size_t)FCH]);
        bf[6] = f2bf(bp[6 * (size_t)FCH]);
        bf[7] = f2bf(bp[7 * (size_t)FCH]);

        acc0 = __builtin_amdgcn_mfma_f32_16x16x32_bf16(af0, bf, acc0, 0, 0, 0);
        acc1 = __builtin_amdgcn_mfma_f32_16x16x32_bf16(af1, bf, acc1, 0, 0, 0);
    }

    float* pout = part + (size_t)kp * 32 * FCH;
    #pragma unroll
    for (int r = 0; r < 4; ++r) {
        pout[(size_t)(q * 4 + r) * FCH + j0 + L15]        = acc0[r];
        pout[(size_t)(16 + q * 4 + r) * FCH + j0 + L15]   = acc1[r];
    }
}

// ---------------------------------------------------------------------------
// K5: out = relu(sum_kp part + b1) @ W2 + b2 ; one block per b.
// ---------------------------------------------------------------------------
__global__ __launch_bounds__(256) void fc2_kernel(
    const float* __restrict__ part, const float* __restrict__ b1,
    const float* __restrict__ W2, const float* __restrict__ b2,
    float* __restrict__ out)
{
    __shared__ float red[4][4];
    const int b = blockIdx.x, tid = threadIdx.x;
    float a0 = 0.f, a1 = 0.f, a2 = 0.f, a3 = 0.f;
    #pragma unroll
    for (int k = 0; k < 4; ++k) {
        int j4 = tid + k * 256;
        float4 hv = make_float4(0.f, 0.f, 0.f, 0.f);
        #pragma unroll
        for (int kp = 0; kp < KPARTS; ++kp) {
            float4 pv = ((const float4*)(part + (size_t)(kp * 32 + b) * FCH))[j4];
            hv.x += pv.x; hv.y += pv.y; hv.z += pv.z; hv.w += pv.w;
        }
        float4 bv = ((const float4*)b1)[j4];
        float h0 = fmaxf(hv.x + bv.x, 0.f), h1 = fmaxf(hv.y + bv.y, 0.f);
        float h2 = fmaxf(hv.z + bv.z, 0.f), h3 = fmaxf(hv.w + bv.w, 0.f);
        float4 w0 = ((const float4*)W2)[j4 * 4 + 0];
        float4 w1 = ((const float4*)W2)[j4 * 4 + 1];
        float4 w2 = ((const float4*)W2)[j4 * 4 + 2];
        float4 w3 = ((const float4*)W2)[j4 * 4 + 3];
        a0 += h0 * w0.x + h1 * w1.x + h2 * w2.x + h3 * w3.x;
        a1 += h0 * w0.y + h1 * w1.y + h2 * w2.y + h3 * w3.y;
        a2 += h0 * w0.z + h1 * w1.z + h2 * w2.z + h3 * w3.z;
        a3 += h0 * w0.w + h1 * w1.w + h2 * w2.w + h3 * w3.w;
    }
    #pragma unroll
    for (int d = 32; d; d >>= 1) {
        a0 += __shfl_xor(a0, d, 64);
        a1 += __shfl_xor(a1, d, 64);
        a2 += __shfl_xor(a2, d, 64);
        a3 += __shfl_xor(a3, d, 64);
    }
    const int wv = tid >> 6, lane = tid & 63;
    if (lane == 0) { red[wv][0] = a0; red[wv][1] = a1; red[wv][2] = a2; red[wv][3] = a3; }
    __syncthreads();
    if (tid < 4) {
        float s = red[0][tid] + red[1][tid] + red[2][tid] + red[3][tid] + b2[tid];
        out[b * OO + tid] = s;
    }
}

// ---------------------------------------------------------------------------
extern "C" void kernel_launch(void* const* d_in, const int* in_sizes, int n_in,
                              void* d_out, int out_size, void* d_ws, size_t ws_size,
                              hipStream_t stream)
{
    const float* x          = (const float*)d_in[0];
    const int*   num_frames = (const int*)  d_in[1];
    const float* query      = (const float*)d_in[2];
    const float* W1         = (const float*)d_in[3];
    const float* b1         = (const float*)d_in[4];
    const float* W2         = (const float*)d_in[5];
    const float* b2         = (const float*)d_in[6];

    float* out      = (float*)d_out;           // (B, O) = 128 floats
    float* attn_out = out + BZ * OO;           // (O, F, B*H) = 1048576 floats

    float*  ws        = (float*)d_ws;
    float*  ws_logits = ws;                        // 1,048,576 floats (4 MB)
    float2* ws_fstats = (float2*)(ws + 1048576);   // 2048 float2 (16 KB, final m/inv)
    float*  ws_hcat   = ws + 1048576 + 4096;       // 131,072 floats (fully written)
    // fc1 partials ALIAS ws_logits: logits are dead after attn_out_kernel
    // (stream-ordered), and part is exactly 8*32*4096 = 1,048,576 floats.
    float*  ws_part   = ws_logits;

    attn_fused_kernel<<<BZ * HH, 256, 0, stream>>>(x, num_frames, query,
                                                   ws_logits, ws_fstats, ws_hcat);
    attn_out_kernel<<<dim3(8, 8, 4), 256, 0, stream>>>(ws_logits, ws_fstats, attn_out);
    fc1_mfma_kernel<<<dim3(64, KPARTS), 256, 0, stream>>>(ws_hcat, W1, ws_part);
    fc2_kernel     <<<BZ, 256, 0, stream>>>(ws_part, b1, W2, b2, out);
}